// Round 5
// baseline (205.682 us; speedup 1.0000x reference)
//
#include <hip/hip_runtime.h>
#include <hip/hip_bf16.h>

// ---- problem constants ----
#define T_TOK 2048
#define HID   1024
#define FF    1024
#define NEXP  8
#define NPAIR 4096

// ---- GEMM tiling ----
#define BM 128
#define BN 128
#define BK 32
#define MAX_MT 40
#define MAXROWS (MAX_MT*BM)   // 5120
#define PPT (NPAIR/256)       // 16
#define NPREP 512             // prep conversion blocks

using bf16x8 = __attribute__((ext_vector_type(8))) __bf16;
using us8    = __attribute__((ext_vector_type(8))) unsigned short;
using f32x4  = __attribute__((ext_vector_type(4))) float;

__device__ __forceinline__ unsigned short f2bf(float f) {
    unsigned int u = __float_as_uint(f);
    return (unsigned short)((u + 0x7FFF + ((u >> 16) & 1)) >> 16);   // RNE
}
__device__ __forceinline__ float bf2f(unsigned short s) {
    return __uint_as_float(((unsigned int)s) << 16);
}

// ---------------- prep: hs fp32->bf16 (blocks 0..NPREP-1) + setup scan (block NPREP) ----
__global__ void prep_kernel(const float* __restrict__ hs,
                            const int* __restrict__ ids,
                            int* __restrict__ pair_pos,
                            int* __restrict__ row_tok,
                            int* __restrict__ meta,
                            unsigned short* __restrict__ hs_b) {
    int tid = threadIdx.x;
    if (blockIdx.x == NPREP) {
        __shared__ int S[2][256][NEXP];
        __shared__ int base[NEXP];
        int myc[NEXP];
        int eloc[PPT];
#pragma unroll
        for (int e = 0; e < NEXP; e++) myc[e] = 0;
#pragma unroll
        for (int i = 0; i < PPT; i++) {
            int e = ids[tid * PPT + i];
            eloc[i] = e;
#pragma unroll
            for (int ee = 0; ee < NEXP; ee++) myc[ee] += (e == ee);
        }
#pragma unroll
        for (int e = 0; e < NEXP; e++) S[0][tid][e] = myc[e];
        __syncthreads();
        int src = 0;
        for (int d = 1; d < 256; d <<= 1) {
#pragma unroll
            for (int e = 0; e < NEXP; e++) {
                int v = S[src][tid][e];
                if (tid >= d) v += S[src][tid - d][e];
                S[src ^ 1][tid][e] = v;
            }
            __syncthreads();
            src ^= 1;
        }
        if (tid == 0) {
            int mt = 0;
            for (int e = 0; e < NEXP; e++) {
                meta[e] = mt;
                base[e] = mt * BM;
                mt += (S[src][255][e] + BM - 1) / BM;
            }
            meta[NEXP] = mt;
        }
        for (int i = tid; i < MAXROWS; i += 256) row_tok[i] = -1;
        __syncthreads();
        int off[NEXP];
#pragma unroll
        for (int e = 0; e < NEXP; e++) off[e] = base[e] + S[src][tid][e] - myc[e];
#pragma unroll
        for (int i = 0; i < PPT; i++) {
            int p = tid * PPT + i;
            int e = eloc[i];
            int pos = 0;
#pragma unroll
            for (int ee = 0; ee < NEXP; ee++) if (e == ee) pos = off[ee]++;
            pair_pos[p] = pos;
            row_tok[pos] = p >> 1;
        }
        return;
    }
    long stride = (long)NPREP * 256;
    const long NH = (long)T_TOK * HID / 4;    // 524288 float4
    for (long i = (long)blockIdx.x * 256 + tid; i < NH; i += stride) {
        float4 v = ((const float4*)hs)[i];
        ushort4 o; o.x = f2bf(v.x); o.y = f2bf(v.y); o.z = f2bf(v.z); o.w = f2bf(v.w);
        ((ushort4*)hs_b)[i] = o;
    }
}

// ---------------- grouped GEMM: register-staged pipeline, fp32 B converted in-flight ----
// EPI==1: A rows indirect via row_tok into hs_b (bf16); B = original wgu fp32,
//         gate/up de-interleaved in staging addressing; epilogue silu(gate)*up -> act bf16.
// EPI==2: A = act (bucket-ordered bf16); B = original wdn fp32; plain bf16 store to ybuf.
template<int EPI, int NBY>
__global__ __launch_bounds__(256)
void gemm_moe(const unsigned short* __restrict__ A,
              const float* __restrict__ Bf,
              unsigned short* __restrict__ Cbf,
              const int* __restrict__ meta,
              const int* __restrict__ row_tok,
              int K, long Bexp) {
    __shared__ unsigned short As[2][BM * BK];   // 16 KB
    __shared__ unsigned short Bs[2][BN * BK];   // 16 KB

    // XCD-locality: xcd = L%8 owns NBY/8 consecutive n-slabs across all bx
    int L = blockIdx.x;
    int xcd = L & 7;
    int slot = L >> 3;
    constexpr int PER = NBY / 8;
    int by = xcd * PER + (slot % PER);
    int bx = slot / PER;
    if (bx >= meta[NEXP]) return;
    int e = 0;
#pragma unroll
    for (int i = 1; i < NEXP; i++) if (bx >= meta[i]) e = i;

    long m0 = (long)bx * BM;
    int n0 = by * BN;

    int tid = threadIdx.x, lane = tid & 63, wv = tid >> 6;
    const int r = lane & 15;
    const int q = lane >> 4;
    const int mw = (wv >> 1) * 64, nw = (wv & 1) * 64;
    const int sw = (q ^ ((r >> 1) & 3)) * 8;   // swizzled k-chunk for frag reads

    // per-thread staging base pointers (2 x 16B-chunks each for A and B)
    const unsigned short* apb[2];
    const float* bpb[2];
#pragma unroll
    for (int h = 0; h < 2; h++) {
        int c = h * 256 + tid;
        int row = c >> 2, cp = c & 3;
        int cc = cp ^ ((row >> 1) & 3);        // global k-chunk held in LDS slot cp
        long ga, gb;
        if (EPI == 1) {
            int tk = row_tok[m0 + row];
            if (tk < 0) tk = 0;                // pad rows: finite garbage, never read
            ga = tk;
            gb = ((row & 1) ? FF : 0) + ((n0 + row) >> 1);   // de-interleave gate/up
        } else {
            ga = m0 + row;
            gb = n0 + row;
        }
        apb[h] = A + ga * (long)K + cc * 8;
        bpb[h] = Bf + (long)e * Bexp + gb * (long)K + cc * 8;
    }

    us8   Ar[2];
    float4 Br[2][2];
    auto ldregs = [&](int k0) {
#pragma unroll
        for (int h = 0; h < 2; h++) {
            Ar[h]    = *(const us8*)(apb[h] + k0);
            Br[h][0] = *(const float4*)(bpb[h] + k0);
            Br[h][1] = *(const float4*)(bpb[h] + k0 + 4);
        }
    };
    auto dswrite = [&](int s) {
#pragma unroll
        for (int h = 0; h < 2; h++) {
            int c = h * 256 + tid;
            *(us8*)&As[s][c * 8] = Ar[h];
            us8 bo;
            float4 x = Br[h][0], y = Br[h][1];
            bo[0] = f2bf(x.x); bo[1] = f2bf(x.y); bo[2] = f2bf(x.z); bo[3] = f2bf(x.w);
            bo[4] = f2bf(y.x); bo[5] = f2bf(y.y); bo[6] = f2bf(y.z); bo[7] = f2bf(y.w);
            *(us8*)&Bs[s][c * 8] = bo;
        }
    };

    f32x4 acc[4][4] = {};
    const int NKI = K / BK;   // 32
    ldregs(0);
    dswrite(0);
    ldregs(BK);
    for (int ki = 0; ki < NKI; ki++) {
        __syncthreads();      // ds_writes to buf[ki&1] visible; prior reads of buf[ki^1] done
        int s = ki & 1;
        bf16x8 a[4], b[4];
#pragma unroll
        for (int i = 0; i < 4; i++)
            a[i] = *(const bf16x8*)&As[s][(mw + i * 16 + r) * BK + sw];
#pragma unroll
        for (int j = 0; j < 4; j++)
            b[j] = *(const bf16x8*)&Bs[s][(nw + j * 16 + r) * BK + sw];
        if (ki + 1 < NKI) dswrite(s ^ 1);          // regs hold k=ki+1
        if (ki + 2 < NKI) ldregs((ki + 2) * BK);   // stays in flight across barriers
#pragma unroll
        for (int i = 0; i < 4; i++)
#pragma unroll
            for (int j = 0; j < 4; j++)
                acc[i][j] = __builtin_amdgcn_mfma_f32_16x16x32_bf16(a[i], b[j], acc[i][j], 0, 0, 0);
    }

    // D layout: row = q*4 + reg, col = lane&15 per 16x16 tile
    if (EPI == 1) {
#pragma unroll
        for (int i = 0; i < 4; i++) {
            long rowb = m0 + mw + i * 16 + q * 4;
#pragma unroll
            for (int j = 0; j < 4; j++) {
                int n = n0 + nw + j * 16 + r;
#pragma unroll
                for (int reg = 0; reg < 4; reg++) {
                    float v = acc[i][j][reg];
                    float o = __shfl_xor(v, 1);
                    if (!(r & 1)) {
                        float g = v, u = o;
                        float s2 = g / (1.f + __expf(-g)) * u;
                        Cbf[(rowb + reg) * (long)FF + (n >> 1)] = f2bf(s2);
                    }
                }
            }
        }
    } else {
#pragma unroll
        for (int i = 0; i < 4; i++) {
            long rowb = m0 + mw + i * 16 + q * 4;
#pragma unroll
            for (int j = 0; j < 4; j++) {
                int n = n0 + nw + j * 16 + r;
#pragma unroll
                for (int reg = 0; reg < 4; reg++)
                    Cbf[(rowb + reg) * (long)HID + n] = f2bf(acc[i][j][reg]);
            }
        }
    }
}

// ---------------- weighted combine ----------------
__global__ void combine_kernel(const unsigned short* __restrict__ y,
                               const float* __restrict__ tw,
                               const int* __restrict__ pair_pos,
                               float* __restrict__ out) {
    int t = blockIdx.x;
    int c = threadIdx.x * 4;
    int p0 = pair_pos[t * 2], p1 = pair_pos[t * 2 + 1];
    float w0 = tw[t * 2], w1 = tw[t * 2 + 1];
    ushort4 a = *(const ushort4*)(y + (long)p0 * HID + c);
    ushort4 b = *(const ushort4*)(y + (long)p1 * HID + c);
    float4 o;
    o.x = w0 * bf2f(a.x) + w1 * bf2f(b.x);
    o.y = w0 * bf2f(a.y) + w1 * bf2f(b.y);
    o.z = w0 * bf2f(a.z) + w1 * bf2f(b.z);
    o.w = w0 * bf2f(a.w) + w1 * bf2f(b.w);
    *(float4*)(out + (long)t * HID + c) = o;
}

extern "C" void kernel_launch(void* const* d_in, const int* in_sizes, int n_in,
                              void* d_out, int out_size, void* d_ws, size_t ws_size,
                              hipStream_t stream) {
    const float* hs  = (const float*)d_in[0];
    const float* tw  = (const float*)d_in[1];
    const int*   ids = (const int*)d_in[2];
    const float* wgu = (const float*)d_in[3];
    const float* wdn = (const float*)d_in[4];
    float* out = (float*)d_out;

    char* ws = (char*)d_ws;
    size_t off = 0;
    auto alloc = [&](size_t bytes) -> void* {
        void* p = ws + off;
        off += (bytes + 255) & ~(size_t)255;
        return p;
    };
    unsigned short* hs_b = (unsigned short*)alloc((size_t)T_TOK * HID * 2);     // 4 MB
    unsigned short* act  = (unsigned short*)alloc((size_t)MAXROWS * FF * 2);    // 10 MB
    unsigned short* ybuf = (unsigned short*)alloc((size_t)MAXROWS * HID * 2);   // 10 MB
    int* pair_pos = (int*)alloc(NPAIR * 4);
    int* row_tok  = (int*)alloc(MAXROWS * 4);
    int* meta     = (int*)alloc(64);

    prep_kernel<<<NPREP + 1, 256, 0, stream>>>(hs, ids, pair_pos, row_tok, meta, hs_b);

    // GEMM1: (rows x 1024) x wgu_e(2048 x 1024)^T [fp32, cvt in staging] -> silu -> act
    gemm_moe<1, 16><<<16 * MAX_MT, 256, 0, stream>>>(
        hs_b, wgu, act, meta, row_tok, HID, (long)(2 * FF) * HID);

    // GEMM2: (rows x 1024) x wdn_e(1024 x 1024)^T [fp32, cvt in staging] -> ybuf bf16
    gemm_moe<2, 8><<<8 * MAX_MT, 256, 0, stream>>>(
        act, wdn, ybuf, meta, row_tok, FF, (long)HID * FF);

    combine_kernel<<<T_TOK, 256, 0, stream>>>(ybuf, tw, pair_pos, out);
}